// Round 3
// baseline (19557.336 us; speedup 1.0000x reference)
//
#include <hip/hip_runtime.h>

// ---------------------------------------------------------------------------
// SequencePredictorRNN: LSTM(1024 steps, batch 128, d=1024) + 512-class readout
// fp32 in global memory (per reference dtypes); fp16 fragments for MFMA,
// fp32 accumulation; fp32 output logits.
//
// Single persistent kernel, 128 blocks x 512 threads (1 block/CU):
//   block b owns hidden units [8b, 8b+8) -> 32 packed gate columns
//   (col' = gate*8 + j; W row = gate*1024 + b*8 + j).
//   Phase A: stage W_ih slice + W_pred slice + biases into LDS (fp32->fp16).
//   Phase B: XGs[class][32] = emb[class,:] . W_ih_slice^T + bias  (only 512
//            distinct x values -> input GEMM becomes a 512-row table).
//   Phase C: restage Ws with W_hh slice.
//   Main loop (1025 iters): gates MFMA vs h_p (global fp16 double buffer),
//   fused logits MFMA for h_p into out[s=p-1], LSTM cell update (c fp32 regs),
//   device-wide barrier (scoped atomics + threadfence).
// Workspace: 256 B counter + 2 x 128x1024 fp16 h buffers = 512.25 KB.
// ---------------------------------------------------------------------------

typedef _Float16 h8v  __attribute__((ext_vector_type(8)));   // 8 x fp16 (4 VGPR)
typedef float    f32x4 __attribute__((ext_vector_type(4)));

#define SEQL  1024
#define BATCH 128
#define DM    1024
#define NC    512
#define PAD   1032

__device__ __forceinline__ float sigm(float x)   { return 1.0f / (1.0f + __expf(-x)); }
__device__ __forceinline__ float tanh_f(float x) { return 1.0f - 2.0f / (__expf(2.0f * x) + 1.0f); }

__device__ __forceinline__ h8v ld8f_cvt(const float* p) {
    const float4 a = ((const float4*)p)[0];
    const float4 b = ((const float4*)p)[1];
    h8v v;
    v[0] = (_Float16)a.x; v[1] = (_Float16)a.y;
    v[2] = (_Float16)a.z; v[3] = (_Float16)a.w;
    v[4] = (_Float16)b.x; v[5] = (_Float16)b.y;
    v[6] = (_Float16)b.z; v[7] = (_Float16)b.w;
    return v;
}

__global__ __launch_bounds__(512) void lstm_all_kernel(
    const int*   __restrict__ x,     const float* __restrict__ emb,
    const float* __restrict__ Wih,   const float* __restrict__ Whh,
    const float* __restrict__ bih,   const float* __restrict__ bhh,
    const float* __restrict__ Wpred, const float* __restrict__ bpred,
    _Float16* __restrict__ hbuf, unsigned* __restrict__ cnt,
    float* __restrict__ out)
{
    __shared__ _Float16 Ws[32 * PAD];      // W_ih slice, then W_hh slice
    __shared__ _Float16 Wp[16 * PAD];      // W_pred slice (16 x 1024)
    __shared__ _Float16 XGs[512 * 32];     // XG table: class x 32 packed cols
    __shared__ float biasS[32];

    const int tid  = threadIdx.x;
    const int b    = blockIdx.x;
    const int u0   = b * 8;                 // first hidden unit owned
    const int C0   = (b & 31) * 16;         // logits column base
    const int wave = tid >> 6, lane = tid & 63;
    const int q = lane >> 4, p15 = lane & 15;

    // ---- Phase A: stage W_ih slice, W_pred slice, biases ----
    for (int idx = tid; idx < 32 * 128; idx += 512) {
        int c = idx >> 7, kc = idx & 127;
        int g = c >> 3, j = c & 7;
        *(h8v*)&Ws[c * PAD + kc * 8] =
            ld8f_cvt(&Wih[(g * 1024 + u0 + j) * DM + kc * 8]);
    }
    for (int idx = tid; idx < 16 * 128; idx += 512) {
        int rr = idx >> 7, kc = idx & 127;
        *(h8v*)&Wp[rr * PAD + kc * 8] =
            ld8f_cvt(&Wpred[(C0 + rr) * DM + kc * 8]);
    }
    if (tid < 32) {
        int g = tid >> 3, j = tid & 7;
        int r = g * 1024 + u0 + j;
        biasS[tid] = bih[r] + bhh[r];
    }
    __syncthreads();

    const _Float16* wsp0 = &Ws[p15 * PAD + q * 8];          // packed cols 0..15
    const _Float16* wsp1 = &Ws[(16 + p15) * PAD + q * 8];   // packed cols 16..31
    const _Float16* wpp  = &Wp[p15 * PAD + q * 8];

    // ---- Phase B: XG table. Each wave: 64 classes (4 m-tiles of 16) ----
#pragma unroll
    for (int mt = 0; mt < 4; ++mt) {
        f32x4 a0 = {0.f,0.f,0.f,0.f}, a1 = {0.f,0.f,0.f,0.f};
        const float* ep = emb + (wave * 64 + mt * 16 + p15) * DM + q * 8;
#pragma unroll 8
        for (int ks = 0; ks < 32; ++ks) {
            h8v av = ld8f_cvt(ep + ks * 32);
            a0 = __builtin_amdgcn_mfma_f32_16x16x32_f16(
                av, *(const h8v*)(wsp0 + ks * 32), a0, 0, 0, 0);
            a1 = __builtin_amdgcn_mfma_f32_16x16x32_f16(
                av, *(const h8v*)(wsp1 + ks * 32), a1, 0, 0, 0);
        }
#pragma unroll
        for (int reg = 0; reg < 4; ++reg) {
            int row = wave * 64 + mt * 16 + q * 4 + reg;    // class index
            XGs[row * 32 + p15]      = (_Float16)(a0[reg] + biasS[p15]);
            XGs[row * 32 + 16 + p15] = (_Float16)(a1[reg] + biasS[16 + p15]);
        }
    }
    __syncthreads();

    // ---- Phase C: restage Ws with W_hh slice ----
    for (int idx = tid; idx < 32 * 128; idx += 512) {
        int c = idx >> 7, kc = idx & 127;
        int g = c >> 3, j = c & 7;
        *(h8v*)&Ws[c * PAD + kc * 8] =
            ld8f_cvt(&Whh[(g * 1024 + u0 + j) * DM + kc * 8]);
    }
    __syncthreads();

    const int wA = (b >> 5) * 2;                       // logits waves
    const bool isLog = (wave == wA) || (wave == wA + 1);
    const float bp_l = isLog ? bpred[C0 + p15] : 0.f;

    float csr[4] = {0.f, 0.f, 0.f, 0.f};               // cell state (fp32)

#pragma unroll 1
    for (int p = 0; p <= SEQL; ++p) {
        const _Float16* hprev = hbuf + (p & 1) * (BATCH * DM);
        _Float16*       hnew  = hbuf + ((p + 1) & 1) * (BATCH * DM);
        const bool doGates = (p < SEQL);
        const bool doLogW  = (p >= 1) && isLog;

        f32x4 accA = {0.f,0.f,0.f,0.f}, accB = {0.f,0.f,0.f,0.f}, accL = {0.f,0.f,0.f,0.f};

        if (doGates || doLogW) {
            if (doGates) {
#pragma unroll
                for (int reg = 0; reg < 4; ++reg) {
                    int row = wave * 16 + q * 4 + reg;     // batch row
                    int cls = x[p * BATCH + row];
                    accA[reg] = (float)XGs[cls * 32 + p15];
                    accB[reg] = (float)XGs[cls * 32 + 16 + p15];
                }
            }
            const _Float16* apt = hprev + (wave * 16 + p15) * DM + q * 8;
#pragma unroll 1
            for (int kc = 0; kc < 4; ++kc) {
                h8v af[8];
#pragma unroll
                for (int jj = 0; jj < 8; ++jj)
                    af[jj] = *(const h8v*)(apt + (kc * 8 + jj) * 32);
#pragma unroll
                for (int jj = 0; jj < 8; ++jj) {
                    int ks = kc * 8 + jj;
                    if (doGates) {
                        accA = __builtin_amdgcn_mfma_f32_16x16x32_f16(
                            af[jj], *(const h8v*)(wsp0 + ks * 32), accA, 0, 0, 0);
                        accB = __builtin_amdgcn_mfma_f32_16x16x32_f16(
                            af[jj], *(const h8v*)(wsp1 + ks * 32), accB, 0, 0, 0);
                    }
                    if (doLogW) {
                        accL = __builtin_amdgcn_mfma_f32_16x16x32_f16(
                            af[jj], *(const h8v*)(wpp + ks * 32), accL, 0, 0, 0);
                    }
                }
            }
        }

        if (doLogW) {                                   // logits for timestep p-1
            int s = p - 1;
#pragma unroll
            for (int reg = 0; reg < 4; ++reg) {
                int row = wave * 16 + q * 4 + reg;      // batch row
                out[row * (SEQL * NC) + s * NC + C0 + p15] = accL[reg] + bp_l;
            }
        }

        if (doGates) {
            // cell update: lane p15<8 owns unit j=p15; lanes p15+8 hold f,o
#pragma unroll
            for (int reg = 0; reg < 4; ++reg) {
                float fv = __shfl_xor(accA[reg], 8, 64);
                float ov = __shfl_xor(accB[reg], 8, 64);
                if (p15 < 8) {
                    float iv = sigm(accA[reg]);
                    float ff = sigm(fv);
                    float gv = tanh_f(accB[reg]);
                    float oo = sigm(ov);
                    float c  = ff * csr[reg] + iv * gv;
                    csr[reg] = c;
                    int row = wave * 16 + q * 4 + reg;
                    hnew[row * DM + u0 + p15] = (_Float16)(oo * tanh_f(c));
                }
            }
            // ---- device-wide barrier ----
            __syncthreads();                 // drains this block's h stores
            if (tid == 0) {
                __threadfence();             // release (L2 writeback)
                __hip_atomic_fetch_add(cnt, 1u, __ATOMIC_RELEASE,
                                       __HIP_MEMORY_SCOPE_AGENT);
                const unsigned target = (unsigned)(p + 1) * gridDim.x;
                while (__hip_atomic_load(cnt, __ATOMIC_ACQUIRE,
                                         __HIP_MEMORY_SCOPE_AGENT) < target)
                    __builtin_amdgcn_s_sleep(1);
                __threadfence();             // acquire (L1/L2 invalidate)
            }
            __syncthreads();
        }
    }
}

// ---------------------------------------------------------------------------
extern "C" void kernel_launch(void* const* d_in, const int* in_sizes, int n_in,
                              void* d_out, int out_size, void* d_ws, size_t ws_size,
                              hipStream_t stream) {
    (void)in_sizes; (void)n_in; (void)out_size; (void)ws_size;
    const int*   x     = (const int*)  d_in[0];
    const float* emb   = (const float*)d_in[1];
    const float* Wih   = (const float*)d_in[2];
    const float* Whh   = (const float*)d_in[3];
    const float* bih   = (const float*)d_in[4];
    const float* bhh   = (const float*)d_in[5];
    const float* Wpred = (const float*)d_in[6];
    const float* bpred = (const float*)d_in[7];
    float* out = (float*)d_out;

    unsigned*  cnt  = (unsigned*)d_ws;                  // barrier counter
    _Float16*  hbuf = (_Float16*)((char*)d_ws + 256);   // 2 x 128x1024 fp16

    // zero barrier counter + h0 buffer (buffer 1 is fully written at p=0)
    hipMemsetAsync(d_ws, 0, 256 + BATCH * DM * 2, stream);

    hipLaunchKernelGGL(lstm_all_kernel, dim3(128), dim3(512), 0, stream,
                       x, emb, Wih, Whh, bih, bhh, Wpred, bpred,
                       hbuf, cnt, out);
}